// Round 1
// baseline (12339.828 us; speedup 1.0000x reference)
//
#include <hip/hip_runtime.h>
#include <hip/hip_cooperative_groups.h>

namespace cg = cooperative_groups;

// Problem constants (fixed by the reference): B=64, T=512, D=1024, R=1024, O=1024
#define BB 64
#define TT 512
#define DD 1024
#define RR 1024

typedef __bf16 bf16x8 __attribute__((ext_vector_type(8)));
typedef float f32x4 __attribute__((ext_vector_type(4)));
typedef unsigned short us4 __attribute__((ext_vector_type(4)));

__device__ inline unsigned short f2bf(float f) {
  unsigned int u = __float_as_uint(f);
  u = (u + 0x7fffu + ((u >> 16) & 1u)) >> 16;   // RNE
  return (unsigned short)u;
}
__device__ inline float bf2f(unsigned short b) {
  return __uint_as_float(((unsigned int)b) << 16);
}

// ---- fp32 -> bf16 vectorized convert (n4 = n/4 groups) ----
__global__ void k_f2b4(const float* __restrict__ in, unsigned short* __restrict__ out, int n4) {
  int i = blockIdx.x * blockDim.x + threadIdx.x;
  if (i < n4) {
    const float4 v = ((const float4*)in)[i];
    us4 o;
    o.x = f2bf(v.x); o.y = f2bf(v.y); o.z = f2bf(v.z); o.w = f2bf(v.w);
    ((us4*)out)[i] = o;
  }
}

// ---- transpose 1024x1024 fp32 -> bf16 (out[j][k] = in[k][j]) ----
__global__ __launch_bounds__(256) void k_transpose_bf16(
    const float* __restrict__ in, unsigned short* __restrict__ out) {
  __shared__ float tile[32][33];
  const int bx = blockIdx.x * 32, by0 = blockIdx.y * 32;
  const int tx = threadIdx.x, ty = threadIdx.y;  // block (32,8)
#pragma unroll
  for (int r = 0; r < 32; r += 8)
    tile[ty + r][tx] = in[(size_t)(by0 + ty + r) * 1024 + bx + tx];
  __syncthreads();
#pragma unroll
  for (int r = 0; r < 32; r += 8)
    out[(size_t)(bx + ty + r) * 1024 + by0 + tx] = f2bf(tile[tx][ty + r]);
}

// ---- async global->LDS, 16B per lane ----
__device__ inline void gload_lds16(const unsigned short* g, unsigned short* l) {
  __builtin_amdgcn_global_load_lds(
      (const __attribute__((address_space(1))) unsigned int*)g,
      (__attribute__((address_space(3))) unsigned int*)l, 16, 0, 0);
}

// ---- bf16 GEMM, C[m,n] = sum_k A[m,k]*B[n,k], 128x128 tile, BK=32 ----
// EPI==0: out = xhz time-major [T][B][2048] bf16, bias folded (bh for n<1024, bz else)
// EPI==1: out[m*1024+n] bf16 (Mz into Wrec rows 1024..2047; pass outb=Wrec+1024*1024)
template <int EPI>
__global__ __launch_bounds__(256) void gemm_bt(
    const unsigned short* __restrict__ A,
    const unsigned short* __restrict__ Bm,
    const float* __restrict__ bias_h,
    const float* __restrict__ bias_z,
    unsigned short* __restrict__ outb, int K) {
  __shared__ __attribute__((aligned(16))) unsigned short As[128 * 32];
  __shared__ __attribute__((aligned(16))) unsigned short Bs[128 * 32];
  const int tid = threadIdx.x;
  const int m0 = blockIdx.y * 128, n0 = blockIdx.x * 128;
  const int lane = tid & 63, wid = tid >> 6;
  const int l16 = lane & 15, quad = lane >> 4;
  const int wm = (wid & 1) * 64, wn = (wid >> 1) * 64;

  f32x4 acc[4][4] = {};

  const int c0 = tid, c1 = 256 + tid;
  const int rowA0 = c0 >> 2, colA0 = (c0 & 3) << 3;
  const int rowA1 = c1 >> 2, colA1 = (c1 & 3) << 3;

  for (int kk = 0; kk < K; kk += 32) {
    __syncthreads();
    gload_lds16(A + (size_t)(m0 + rowA0) * K + kk + colA0, As + c0 * 8);
    gload_lds16(A + (size_t)(m0 + rowA1) * K + kk + colA1, As + c1 * 8);
    gload_lds16(Bm + (size_t)(n0 + rowA0) * K + kk + colA0, Bs + c0 * 8);
    gload_lds16(Bm + (size_t)(n0 + rowA1) * K + kk + colA1, Bs + c1 * 8);
    __syncthreads();
    bf16x8 af[4], bfr[4];
#pragma unroll
    for (int i = 0; i < 4; ++i) {
      af[i] = *(const bf16x8*)&As[(wm + i * 16 + l16) * 32 + quad * 8];
      bfr[i] = *(const bf16x8*)&Bs[(wn + i * 16 + l16) * 32 + quad * 8];
    }
#pragma unroll
    for (int i = 0; i < 4; ++i)
#pragma unroll
      for (int j = 0; j < 4; ++j)
        acc[i][j] = __builtin_amdgcn_mfma_f32_16x16x32_bf16(af[i], bfr[j], acc[i][j], 0, 0, 0);
  }

#pragma unroll
  for (int i = 0; i < 4; ++i) {
#pragma unroll
    for (int j = 0; j < 4; ++j) {
#pragma unroll
      for (int r = 0; r < 4; ++r) {
        const int m = m0 + wm + i * 16 + quad * 4 + r;
        const int n = n0 + wn + j * 16 + l16;
        float v = acc[i][j][r];
        if (EPI == 0) {
          v += (n < 1024) ? bias_h[n] : bias_z[n - 1024];
          const int b = m >> 9;          // m = b*T + t, T=512
          const int t = m & 511;
          outb[((size_t)(t * 64 + b) << 11) + n] = f2bf(v);
        } else {
          outb[(size_t)m * 1024 + n] = f2bf(v);
        }
      }
    }
  }
}

// ---- persistent cooperative scan over T=512 steps + output GEMM ----
// 128 blocks x 256 threads. Block g owns h-columns [g*8, g*8+8); its 16-wide
// MFMA n-tile = {Whh rows i0..i0+7} U {Mz rows (stored at Wrec rows 1024+i0..)}.
// Waves split K (256 each); LDS reduction; one grid.sync per step.
__global__ __launch_bounds__(256) void scan_out_k(
    const unsigned short* __restrict__ xhz,   // [T][B][2048] bf16
    const unsigned short* __restrict__ Wrec,  // [2048][1024] bf16 (Whh ; Mz)
    const unsigned short* __restrict__ Wyb,   // [1024][1024] bf16
    const float* __restrict__ by,
    float* __restrict__ h0, float* __restrict__ h1,          // fp32 master h (double buf)
    unsigned short* __restrict__ hb0, unsigned short* __restrict__ hb1,  // bf16 copies
    float* __restrict__ out) {
  __shared__ float red[4][64][20];  // stride 20: quad offset = 80 words -> 2-way (free)
  cg::grid_group grid = cg::this_grid();
  const int tid = threadIdx.x, g = blockIdx.x;
  const int lane = tid & 63, wid = tid >> 6;
  const int l16 = lane & 15, quad = lane >> 4;
  const int kw = wid * 256;
  const int i0 = g * 8;
  const int brow = (l16 < 8) ? (i0 + l16) : (1024 + i0 + (l16 - 8));
  const unsigned short* Bb = Wrec + (size_t)brow * 1024 + kw + quad * 8;

  float* hc = h0; float* hn = h1;
  unsigned short* hbc = hb0; unsigned short* hbn = hb1;

  for (int t = 0; t < TT; ++t) {
    f32x4 acc[4] = {};
#pragma unroll
    for (int s = 0; s < 8; ++s) {
      const bf16x8 bfr = *(const bf16x8*)(Bb + s * 32);
#pragma unroll
      for (int mt = 0; mt < 4; ++mt) {
        const bf16x8 afr = *(const bf16x8*)(hbc + (size_t)(mt * 16 + l16) * 1024 + kw + s * 32 + quad * 8);
        acc[mt] = __builtin_amdgcn_mfma_f32_16x16x32_bf16(afr, bfr, acc[mt], 0, 0, 0);
      }
    }
#pragma unroll
    for (int mt = 0; mt < 4; ++mt)
#pragma unroll
      for (int r = 0; r < 4; ++r)
        red[wid][mt * 16 + quad * 4 + r][l16] = acc[mt][r];
    __syncthreads();
#pragma unroll
    for (int p0 = 0; p0 < 2; ++p0) {
      const int p = p0 * 256 + tid;        // 512 (b, il) pairs
      const int b = p >> 3, il = p & 7;
      const int i = i0 + il;
      const float ph = red[0][b][il] + red[1][b][il] + red[2][b][il] + red[3][b][il];
      const float pz = red[0][b][il + 8] + red[1][b][il + 8] + red[2][b][il + 8] + red[3][b][il + 8];
      const size_t xoff = (size_t)(t * 64 + b) << 11;
      const float xh = bf2f(xhz[xoff + i]);
      const float xz = bf2f(xhz[xoff + 1024 + i]);
      const float hold = hc[b * 1024 + i];
      const float z = 1.0f / (1.0f + __expf(-(xz + pz)));
      const float hbv = fmaxf(xh + ph, 0.0f);
      const float hv = z * hold + (1.0f - z) * hbv;
      hn[b * 1024 + i] = hv;
      hbn[b * 1024 + i] = f2bf(hv);
    }
    { float* tmp = hc; hc = hn; hn = tmp; }
    { unsigned short* tmp = hbc; hbc = hbn; hbn = tmp; }
    grid.sync();
  }

  // out = h_final @ Wy^T + by ; final h (bf16) is in hbc (== hb0 after 512 swaps)
  if (g < 64) {
    const int o0 = g * 16;
    const unsigned short* Byb = Wyb + (size_t)(o0 + l16) * 1024 + kw + quad * 8;
    f32x4 acc[4] = {};
#pragma unroll
    for (int s = 0; s < 8; ++s) {
      const bf16x8 bfr = *(const bf16x8*)(Byb + s * 32);
#pragma unroll
      for (int mt = 0; mt < 4; ++mt) {
        const bf16x8 afr = *(const bf16x8*)(hbc + (size_t)(mt * 16 + l16) * 1024 + kw + s * 32 + quad * 8);
        acc[mt] = __builtin_amdgcn_mfma_f32_16x16x32_bf16(afr, bfr, acc[mt], 0, 0, 0);
      }
    }
#pragma unroll
    for (int mt = 0; mt < 4; ++mt)
#pragma unroll
      for (int r = 0; r < 4; ++r)
        red[wid][mt * 16 + quad * 4 + r][l16] = acc[mt][r];
    __syncthreads();
#pragma unroll
    for (int j = 0; j < 4; ++j) {
      const int p = j * 256 + tid;
      const int b = p >> 4, oc = p & 15;
      const float v = red[0][b][oc] + red[1][b][oc] + red[2][b][oc] + red[3][b][oc] + by[o0 + oc];
      out[(size_t)b * 1024 + o0 + oc] = v;
    }
  }
}

extern "C" void kernel_launch(void* const* d_in, const int* in_sizes, int n_in,
                              void* d_out, int out_size, void* d_ws, size_t ws_size,
                              hipStream_t stream) {
  const float* x = (const float*)d_in[0];
  const float* Wxh = (const float*)d_in[1];
  const float* bh = (const float*)d_in[2];
  const float* Whh = (const float*)d_in[3];
  const float* Wxz = (const float*)d_in[4];
  const float* bz = (const float*)d_in[5];
  const float* Whz = (const float*)d_in[6];
  const float* Wy = (const float*)d_in[7];
  const float* by = (const float*)d_in[8];
  float* out = (float*)d_out;

  char* ws = (char*)d_ws;
  size_t off = 0;
  auto alloc = [&](size_t bytes) -> void* {
    void* p = ws + off;
    off += (bytes + 255) & ~(size_t)255;
    return p;
  };
  const size_t nX = (size_t)BB * TT * DD;  // 33554432
  unsigned short* xb = (unsigned short*)alloc(nX * 2);                  // x bf16
  unsigned short* Wcat = (unsigned short*)alloc((size_t)2048 * 1024 * 2);  // [Wxh;Wxz] bf16
  unsigned short* WhzT = (unsigned short*)alloc((size_t)1024 * 1024 * 2);  // Whz^T bf16
  unsigned short* Wrec = (unsigned short*)alloc((size_t)2048 * 1024 * 2);  // [Whh;Mz] bf16
  unsigned short* Wyb = (unsigned short*)alloc((size_t)1024 * 1024 * 2);   // Wy bf16
  unsigned short* xhz = (unsigned short*)alloc((size_t)TT * BB * 2048 * 2);  // 128 MB
  float* h0 = (float*)alloc((size_t)BB * RR * 4);
  float* h1 = (float*)alloc((size_t)BB * RR * 4);
  unsigned short* hb0 = (unsigned short*)alloc((size_t)BB * RR * 2);
  unsigned short* hb1 = (unsigned short*)alloc((size_t)BB * RR * 2);

  hipMemsetAsync(h0, 0, (size_t)BB * RR * 4, stream);
  hipMemsetAsync(hb0, 0, (size_t)BB * RR * 2, stream);

  // weight / input conversions
  k_f2b4<<<dim3((unsigned)(nX / 4 / 256)), 256, 0, stream>>>(x, xb, (int)(nX / 4));
  k_f2b4<<<dim3(1024), 256, 0, stream>>>(Wxh, Wcat, 262144);
  k_f2b4<<<dim3(1024), 256, 0, stream>>>(Wxz, Wcat + 1024 * 1024, 262144);
  k_f2b4<<<dim3(1024), 256, 0, stream>>>(Whh, Wrec, 262144);
  k_f2b4<<<dim3(1024), 256, 0, stream>>>(Wy, Wyb, 262144);
  k_transpose_bf16<<<dim3(32, 32), dim3(32, 8), 0, stream>>>(Whz, WhzT);

  // Mz = Wxz @ Whz  -> Wrec rows 1024..2047
  gemm_bt<1><<<dim3(8, 8), 256, 0, stream>>>(Wcat + 1024 * 1024, WhzT, nullptr, nullptr,
                                             Wrec + (size_t)1024 * 1024, 1024);
  // xhz = x @ [Wxh;Wxz]^T + [bh;bz], time-major
  gemm_bt<0><<<dim3(16, 256), 256, 0, stream>>>(xb, Wcat, bh, bz, xhz, 1024);

  // cooperative scan + output
  const unsigned short* xhz_c = xhz;
  const unsigned short* Wrec_c = Wrec;
  const unsigned short* Wyb_c = Wyb;
  const float* by_c = by;
  void* kargs[] = {(void*)&xhz_c, (void*)&Wrec_c, (void*)&Wyb_c, (void*)&by_c,
                   (void*)&h0, (void*)&h1, (void*)&hb0, (void*)&hb1, (void*)&out};
  hipLaunchCooperativeKernel((void*)scan_out_k, dim3(128), dim3(256), kargs, 0, stream);
}